// Round 1
// 995.925 us; speedup vs baseline: 1.1819x; 1.1819x over previous
//
#include <hip/hip_runtime.h>
#include <hip/hip_bf16.h>
#include <stdint.h>

#define NTOK 8192
#define DM 2048
#define DH 2048
#define NEXP 8
#define TOPK 2
#define TASSIGN (NTOK * TOPK)   // 16384
#define CAP 2560                // int(1.25 * TOPK * NTOK / NEXP)
#define MROWS (NEXP * CAP)      // 20480
#define BMTILES 10              // CAP / 256

using bf16x8 = __attribute__((ext_vector_type(8))) __bf16;
using bf16x2 = __attribute__((ext_vector_type(2))) __bf16;
using f32x4  = __attribute__((ext_vector_type(4))) float;

__device__ __forceinline__ void load_lds16(const void* g, void* l) {
    __builtin_amdgcn_global_load_lds((const __attribute__((address_space(1))) void*)g,
                                     (__attribute__((address_space(3))) void*)l,
                                     16, 0, 0);
}

// ---------------- routing: stable per-expert ranks ----------------
__global__ void routing_kernel(const int* __restrict__ eidx,
                               int* __restrict__ counts,
                               int* __restrict__ slot_token,
                               int* __restrict__ assign_slot,
                               float* __restrict__ counts_out)
{
    __shared__ int base[NEXP];
    __shared__ int wcnt[4][NEXP];
    int tid = threadIdx.x, lane = tid & 63, wid = tid >> 6;
    for (int i = tid; i < MROWS; i += 256) slot_token[i] = -1;
    if (tid < NEXP) base[tid] = 0;
    __syncthreads();
    for (int t0 = 0; t0 < TASSIGN; t0 += 256) {
        int t = t0 + tid;
        int e = eidx[t];
        unsigned long long mymask = 0;
        #pragma unroll
        for (int ex = 0; ex < NEXP; ex++) {
            unsigned long long m = __ballot(e == ex);
            if (ex == e) mymask = m;
            if (lane == 0) wcnt[wid][ex] = __popcll(m);
        }
        int rankw = __popcll(mymask & ((1ull << lane) - 1ull));
        __syncthreads();
        int prev = base[e];
        for (int w = 0; w < wid; w++) prev += wcnt[w][e];
        int r = prev + rankw;
        int slot = (r < CAP) ? (e * CAP + r) : -1;
        assign_slot[t] = slot;
        if (slot >= 0) slot_token[slot] = t >> 1;  // token = assignment / TOPK
        __syncthreads();
        if (tid < NEXP) {
            int s = 0;
            for (int w = 0; w < 4; w++) s += wcnt[w][tid];
            base[tid] += s;
        }
        __syncthreads();
    }
    if (tid < NEXP) {
        counts[tid] = base[tid];
        counts_out[tid] = (float)base[tid];  // output 1 compared as float32
    }
}

// ---------------- weight transpose + fp32->bf16 convert ----------------
// src: [K=2048][N=2048] fp32 ; dst: [N][K] bf16
__global__ void transpose_kernel(const float* __restrict__ wa,
                                 const float* __restrict__ wb,
                                 const float* __restrict__ wc,
                                 __bf16* __restrict__ wat,
                                 __bf16* __restrict__ wbt,
                                 __bf16* __restrict__ wct)
{
    __shared__ float tile[64][65];
    int z = blockIdx.z;
    int mat = z >> 3, e = z & 7;
    const float* src = (mat == 0 ? wa : mat == 1 ? wb : wc) + (size_t)e * DM * DH;
    __bf16* dst = (mat == 0 ? wat : mat == 1 ? wbt : wct) + (size_t)e * DM * DH;
    int k0 = blockIdx.x * 64, n0 = blockIdx.y * 64;
    int tid = threadIdx.x;
    #pragma unroll
    for (int i = 0; i < 16; i++) {
        int lin = tid + i * 256;
        int r = lin >> 6, c = lin & 63;
        tile[r][c] = src[(size_t)(k0 + r) * DH + (n0 + c)];
    }
    __syncthreads();
    #pragma unroll
    for (int i = 0; i < 8; i++) {
        int lin = tid + i * 256;
        int r = lin >> 5, p = lin & 31;
        int c = p * 2;
        bf16x2 v;
        v[0] = (__bf16)tile[c][r];
        v[1] = (__bf16)tile[c + 1][r];
        *(bf16x2*)(dst + (size_t)(n0 + r) * DM + (k0 + c)) = v;
    }
}

// ---------------- gather x rows into padded bf16 bins ----------------
__global__ void gather_kernel(const float* __restrict__ x,
                              const int* __restrict__ slot_token,
                              __bf16* __restrict__ xg)
{
    int slot = blockIdx.x;
    int tok = slot_token[slot];
    int c = threadIdx.x * 8;
    float f[8];
    if (tok >= 0) {
        const float4* px = (const float4*)(x + (size_t)tok * DM + c);
        float4 a = px[0], b = px[1];
        f[0] = a.x; f[1] = a.y; f[2] = a.z; f[3] = a.w;
        f[4] = b.x; f[5] = b.y; f[6] = b.z; f[7] = b.w;
    } else {
        #pragma unroll
        for (int i = 0; i < 8; i++) f[i] = 0.f;
    }
    bf16x8 v;
    #pragma unroll
    for (int i = 0; i < 8; i++) v[i] = (__bf16)f[i];
    *(bf16x8*)(xg + (size_t)slot * DM + c) = v;
}

// ---------------- grouped GEMM, 256-tile 4-phase counted-vmcnt schedule ----
// A: [MROWS][K] bf16 row-major. B1/B2: [E][N][K] bf16 (pre-transposed).
// FUSED: BN=128, C = silu(A@B1t) * (A@B2t); else BN=256, C = A@B1t.
// LDS per buffer (64KB): A [256][64] @0, B-units @32768 (+16384).
// Swizzle: within each 128B LDS row, 16B-chunk ^= (row&7); applied at the
// global SOURCE of global_load_lds (dest linear) and on the ds_read address.
template<bool FUSED>
__global__ __launch_bounds__(512, 2)
void gemm8_kernel(const __bf16* __restrict__ A,
                  const __bf16* __restrict__ B1,
                  const __bf16* __restrict__ B2,
                  __bf16* __restrict__ C,
                  const int* __restrict__ counts)
{
    constexpr int K = 2048, N = 2048;
    constexpr int BM = 256;
    constexpr int BN = FUSED ? 128 : 256;
    constexpr int NT = K / 64;           // 32 K-tiles
    constexpr int NJ = FUSED ? 2 : 4;    // N-fragments per wave (per B matrix)
    constexpr int ROWB = K * 2;          // 4096B global row stride

    extern __shared__ char smem[];       // 131072 bytes (2 x 64KB buffers)

    int mtile = blockIdx.x, ntile = blockIdx.y;
    int e = mtile / BMTILES;
    int mloc = (mtile % BMTILES) * BM;
    int rows = counts[e]; if (rows > CAP) rows = CAP;
    if (mloc >= rows) return;            // expert bin empty in this tile

    int tid = threadIdx.x;
    int wid = tid >> 6, lane = tid & 63;
    int wm = wid & 1, wn = wid >> 1;     // 2 x 4 wave grid
    size_t rowBase = (size_t)e * CAP + mloc;

    // ---- staging source pointers (per-thread, swizzled chunk) ----
    int r0 = tid >> 3;                            // 0..63 rows per 8KB issue
    int sw = ((tid & 7) ^ (r0 & 7)) << 4;         // chunk swizzle (row&7 invariant mod 64/128)
    const char* sA = (const char*)(A + (rowBase + r0) * (size_t)K) + sw;
    const char* sBu0; const char* sBu1;
    {
        size_t brow = (size_t)e * N + (size_t)ntile * BN + r0;
        sBu0 = (const char*)(B1 + brow * (size_t)K) + sw;
        if constexpr (FUSED) sBu1 = (const char*)(B2 + brow * (size_t)K) + sw;
        else                 sBu1 = sBu0 + 128 * ROWB;
    }
    char* lw = smem + wid * 1024;        // wave-uniform LDS base slice

    // one 16KB unit = 128 rows x 128B; 2 x global_load_lds(16B) per thread
    auto stage2 = [&](const char* s, int koff, int ldsOff) {
        load_lds16(s + koff, lw + ldsOff);
        load_lds16(s + koff + 64 * ROWB, lw + ldsOff + 8192);
    };

    // ---- fragment read offsets (swizzled) ----
    int xc0 = (((lane >> 4) + 0) ^ (lane & 7)) << 4;   // ks=0 16B chunk
    int xc1 = (((lane >> 4) + 4) ^ (lane & 7)) << 4;   // ks=1
    int aOff = (wm * 128 + (lane & 15)) * 128;
    int bOff1, bOff2 = 0;
    if constexpr (FUSED) {
        bOff1 = 32768 + (wn * 32 + (lane & 15)) * 128;
        bOff2 = bOff1 + 16384;
    } else {
        bOff1 = 32768 + (wn * 64 + (lane & 15)) * 128;
    }

    f32x4 acc1[8][NJ];
    f32x4 acc2[FUSED ? 8 : 1][NJ];
    #pragma unroll
    for (int i = 0; i < 8; i++)
        #pragma unroll
        for (int j = 0; j < NJ; j++) {
            acc1[i][j] = (f32x4){0.f, 0.f, 0.f, 0.f};
            if constexpr (FUSED) acc2[i][j] = (f32x4){0.f, 0.f, 0.f, 0.f};
        }

    // ---- prologue: tile0 fully + tile1 B-units; leave t1.B in flight ----
    stage2(sA,              0, 0);
    stage2(sA + 128 * ROWB, 0, 16384);
    stage2(sBu0,            0, 32768);
    stage2(sBu1,            0, 49152);
    stage2(sBu0,          128, 65536 + 32768);
    stage2(sBu1,          128, 65536 + 49152);
    asm volatile("s_waitcnt vmcnt(4)" ::: "memory");   // tile0 landed
    __builtin_amdgcn_sched_barrier(0);
    __builtin_amdgcn_s_barrier();

    bf16x8 b1f[NJ][2];
    bf16x8 b2f[FUSED ? NJ : 1][2];

    #pragma unroll 2
    for (int t = 0; t < NT; ++t) {
        int bufC = (t & 1) << 16;
        int bufO = bufC ^ 65536;
        #pragma unroll
        for (int p = 0; p < 4; ++p) {
            // --- ds_read register subtile ---
            bf16x8 a[2][2];
            #pragma unroll
            for (int i2 = 0; i2 < 2; ++i2) {
                const char* ap = smem + bufC + aOff + (2 * p + i2) * 2048;
                a[i2][0] = *(const bf16x8*)(ap + xc0);
                a[i2][1] = *(const bf16x8*)(ap + xc1);
            }
            if (p == 0) {   // all B fragments once per K-tile -> B region free after p0
                #pragma unroll
                for (int j = 0; j < NJ; ++j) {
                    const char* bp = smem + bufC + bOff1 + j * 2048;
                    b1f[j][0] = *(const bf16x8*)(bp + xc0);
                    b1f[j][1] = *(const bf16x8*)(bp + xc1);
                    if constexpr (FUSED) {
                        const char* bp2 = smem + bufC + bOff2 + j * 2048;
                        b2f[j][0] = *(const bf16x8*)(bp2 + xc0);
                        b2f[j][1] = *(const bf16x8*)(bp2 + xc1);
                    }
                }
            }
            // --- issue one half-tile prefetch (never drained mid-loop) ---
            if (p == 0)      { if (t + 1 < NT) stage2(sA,              (t + 1) * 128, bufO); }
            else if (p == 1) { if (t + 1 < NT) stage2(sA + 128 * ROWB, (t + 1) * 128, bufO + 16384); }
            else if (p == 2) { if (t + 2 < NT) stage2(sBu0,            (t + 2) * 128, bufC + 32768); }
            else             { if (t + 2 < NT) stage2(sBu1,            (t + 2) * 128, bufC + 49152); }

            __builtin_amdgcn_s_barrier();
            asm volatile("s_waitcnt lgkmcnt(0)" ::: "memory");
            __builtin_amdgcn_sched_barrier(0);
            __builtin_amdgcn_s_setprio(1);
            #pragma unroll
            for (int ks = 0; ks < 2; ++ks)
                #pragma unroll
                for (int i2 = 0; i2 < 2; ++i2)
                    #pragma unroll
                    for (int j = 0; j < NJ; ++j) {
                        acc1[2 * p + i2][j] = __builtin_amdgcn_mfma_f32_16x16x32_bf16(
                            a[i2][ks], b1f[j][ks], acc1[2 * p + i2][j], 0, 0, 0);
                        if constexpr (FUSED)
                            acc2[2 * p + i2][j] = __builtin_amdgcn_mfma_f32_16x16x32_bf16(
                                a[i2][ks], b2f[j][ks], acc2[2 * p + i2][j], 0, 0, 0);
                    }
            __builtin_amdgcn_s_setprio(0);
            __builtin_amdgcn_sched_barrier(0);
            if (p == 3) {   // tile boundary: next tile landed, 2 units may fly
                if (t + 2 < NT)      { asm volatile("s_waitcnt vmcnt(4)" ::: "memory"); }
                else if (t + 1 < NT) { asm volatile("s_waitcnt vmcnt(0)" ::: "memory"); }
                __builtin_amdgcn_sched_barrier(0);
            }
            __builtin_amdgcn_s_barrier();
        }
    }

    // ---- epilogue: C/D layout col = lane&15, row = (lane>>4)*4 + reg ----
    size_t crow0 = rowBase + wm * 128 + ((lane >> 4) << 2);
    int col0 = ntile * BN + wn * (FUSED ? 32 : 64) + (lane & 15);
    #pragma unroll
    for (int i = 0; i < 8; ++i)
        #pragma unroll
        for (int j = 0; j < NJ; ++j)
            #pragma unroll
            for (int r = 0; r < 4; ++r) {
                float v = acc1[i][j][r];
                if constexpr (FUSED) {
                    float z3 = acc2[i][j][r];
                    v = (v / (1.f + __expf(-v))) * z3;   // silu(z1) * z3
                }
                C[(crow0 + i * 16 + r) * (size_t)N + (col0 + j * 16)] = (__bf16)v;
            }
}

// ---------------- weighted combine back to tokens ----------------
__global__ void combine_kernel(const __bf16* __restrict__ y,
                               const int* __restrict__ assign_slot,
                               const float* __restrict__ ew,
                               float* __restrict__ out)
{
    int n = blockIdx.x;
    int s0 = assign_slot[2 * n], s1 = assign_slot[2 * n + 1];
    float w0 = ew[2 * n], w1 = ew[2 * n + 1];
    int c = threadIdx.x * 8;
    float acc[8];
    #pragma unroll
    for (int i = 0; i < 8; i++) acc[i] = 0.f;
    if (s0 >= 0) {
        bf16x8 v = *(const bf16x8*)(y + (size_t)s0 * DM + c);
        #pragma unroll
        for (int i = 0; i < 8; i++) acc[i] += w0 * (float)v[i];
    }
    if (s1 >= 0) {
        bf16x8 v = *(const bf16x8*)(y + (size_t)s1 * DM + c);
        #pragma unroll
        for (int i = 0; i < 8; i++) acc[i] += w1 * (float)v[i];
    }
    float4* po = (float4*)(out + (size_t)n * DM + c);
    po[0] = (float4){acc[0], acc[1], acc[2], acc[3]};
    po[1] = (float4){acc[4], acc[5], acc[6], acc[7]};
}

extern "C" void kernel_launch(void* const* d_in, const int* in_sizes, int n_in,
                              void* d_out, int out_size, void* d_ws, size_t ws_size,
                              hipStream_t stream)
{
    const float* x  = (const float*)d_in[0];
    const float* ew = (const float*)d_in[1];
    const int* eidx = (const int*)d_in[2];
    const float* w1 = (const float*)d_in[3];
    const float* w2 = (const float*)d_in[4];
    const float* w3 = (const float*)d_in[5];
    float* out = (float*)d_out;
    float* counts_out = out + (size_t)NTOK * DM;

    char* ws = (char*)d_ws;
    size_t off = 0;
    auto alloc = [&](size_t bytes) -> void* {
        off = (off + 255) & ~(size_t)255;
        void* p = ws + off;
        off += bytes;
        return p;
    };
    int* slot_token  = (int*)alloc((size_t)MROWS * 4);
    int* assign_slot = (int*)alloc((size_t)TASSIGN * 4);
    int* counts      = (int*)alloc(NEXP * 4);
    __bf16* xg  = (__bf16*)alloc((size_t)MROWS * DM * 2);
    __bf16* h   = (__bf16*)alloc((size_t)MROWS * DH * 2);
    __bf16* w1t = (__bf16*)alloc((size_t)NEXP * DM * DH * 2);
    __bf16* w3t = (__bf16*)alloc((size_t)NEXP * DM * DH * 2);
    __bf16* w2t = (__bf16*)alloc((size_t)NEXP * DM * DH * 2);
    __bf16* y = xg;  // xg dead after gemm1 -> reuse for y

    static int attr_done = 0;
    if (!attr_done) {
        hipFuncSetAttribute((const void*)gemm8_kernel<true>,
                            hipFuncAttributeMaxDynamicSharedMemorySize, 131072);
        hipFuncSetAttribute((const void*)gemm8_kernel<false>,
                            hipFuncAttributeMaxDynamicSharedMemorySize, 131072);
        attr_done = 1;
    }

    routing_kernel<<<1, 256, 0, stream>>>(eidx, counts, slot_token, assign_slot, counts_out);
    transpose_kernel<<<dim3(32, 32, 24), 256, 0, stream>>>(w1, w3, w2, w1t, w3t, w2t);
    gather_kernel<<<MROWS, 256, 0, stream>>>(x, slot_token, xg);
    gemm8_kernel<true><<<dim3(NEXP * BMTILES, 16), 512, 131072, stream>>>(xg, w1t, w3t, h, counts);
    gemm8_kernel<false><<<dim3(NEXP * BMTILES, 8), 512, 131072, stream>>>(h, w2t, nullptr, y, counts);
    combine_kernel<<<NTOK, 256, 0, stream>>>(y, assign_slot, ew, out);
}

// Round 2
// 923.093 us; speedup vs baseline: 1.2751x; 1.0789x over previous
//
#include <hip/hip_runtime.h>
#include <hip/hip_bf16.h>
#include <stdint.h>

#define NTOK 8192
#define DM 2048
#define DH 2048
#define NEXP 8
#define TOPK 2
#define TASSIGN (NTOK * TOPK)   // 16384
#define CAP 2560                // int(1.25 * TOPK * NTOK / NEXP)
#define MROWS (NEXP * CAP)      // 20480
#define BMTILES 10              // CAP / 256
#define RBLK 64                 // routing chunks (256 assignments each)

using bf16x8 = __attribute__((ext_vector_type(8))) __bf16;
using f32x4  = __attribute__((ext_vector_type(4))) float;

__device__ __forceinline__ void load_lds16(const void* g, void* l) {
    __builtin_amdgcn_global_load_lds((const __attribute__((address_space(1))) void*)g,
                                     (__attribute__((address_space(3))) void*)l,
                                     16, 0, 0);
}

// ---------------- routing, split: hist -> scan -> assign ----------------
__global__ void route_hist_kernel(const int* __restrict__ eidx,
                                  int* __restrict__ chunk_cnt,
                                  int* __restrict__ slot_token)
{
    int b = blockIdx.x, tid = threadIdx.x, lane = tid & 63, wid = tid >> 6;
    __shared__ int wcnt[4][NEXP];
    // init slot_token: 64 blocks x 320 entries = 20480
    for (int i = b * 320 + tid; i < (b + 1) * 320; i += 256) slot_token[i] = -1;
    int e = eidx[b * 256 + tid];
    #pragma unroll
    for (int ex = 0; ex < NEXP; ex++) {
        unsigned long long m = __ballot(e == ex);
        if (lane == 0) wcnt[wid][ex] = __popcll(m);
    }
    __syncthreads();
    if (tid < NEXP) {
        int s = 0;
        #pragma unroll
        for (int w = 0; w < 4; w++) s += wcnt[w][tid];
        chunk_cnt[b * NEXP + tid] = s;
    }
}

__global__ void route_scan_kernel(const int* __restrict__ chunk_cnt,
                                  int* __restrict__ chunk_base,
                                  int* __restrict__ counts,
                                  float* __restrict__ counts_out)
{
    int e = threadIdx.x;
    if (e < NEXP) {
        int run = 0;
        for (int b = 0; b < RBLK; b++) {
            chunk_base[b * NEXP + e] = run;
            run += chunk_cnt[b * NEXP + e];
        }
        counts[e] = run;
        counts_out[e] = (float)run;   // output 1 compared as float32
    }
}

__global__ void route_assign_kernel(const int* __restrict__ eidx,
                                    const int* __restrict__ chunk_base,
                                    int* __restrict__ slot_token,
                                    int* __restrict__ assign_slot)
{
    int b = blockIdx.x, tid = threadIdx.x, lane = tid & 63, wid = tid >> 6;
    __shared__ int wcnt[4][NEXP];
    int t = b * 256 + tid;
    int e = eidx[t];
    unsigned long long mymask = 0;
    #pragma unroll
    for (int ex = 0; ex < NEXP; ex++) {
        unsigned long long m = __ballot(e == ex);
        if (ex == e) mymask = m;
        if (lane == 0) wcnt[wid][ex] = __popcll(m);
    }
    int rankw = __popcll(mymask & ((1ull << lane) - 1ull));
    __syncthreads();
    int r = chunk_base[b * NEXP + e] + rankw;
    for (int w = 0; w < wid; w++) r += wcnt[w][e];
    int slot = (r < CAP) ? (e * CAP + r) : -1;
    assign_slot[t] = slot;
    if (slot >= 0) slot_token[slot] = t >> 1;  // token = assignment / TOPK
}

// ---------------- weight transpose + fp32->bf16 convert ----------------
// src: [K=2048][N=2048] fp32 ; dst: [N][K] bf16
__global__ void transpose_kernel(const float* __restrict__ wa,
                                 const float* __restrict__ wb,
                                 const float* __restrict__ wc,
                                 __bf16* __restrict__ wat,
                                 __bf16* __restrict__ wbt,
                                 __bf16* __restrict__ wct)
{
    __shared__ float tile[64][65];
    int z = blockIdx.z;
    int mat = z >> 3, e = z & 7;
    const float* src = (mat == 0 ? wa : mat == 1 ? wb : wc) + (size_t)e * DM * DH;
    __bf16* dst = (mat == 0 ? wat : mat == 1 ? wbt : wct) + (size_t)e * DM * DH;
    int k0 = blockIdx.x * 64, n0 = blockIdx.y * 64;
    int tid = threadIdx.x;
    #pragma unroll
    for (int i = 0; i < 16; i++) {
        int lin = tid + i * 256;
        int r = lin >> 6, c = lin & 63;
        tile[r][c] = src[(size_t)(k0 + r) * DH + (n0 + c)];
    }
    __syncthreads();
    // 16B-per-lane stores: n-row = tid>>3 (+32), k-chunk = (tid&7)*8
    #pragma unroll
    for (int i = 0; i < 2; i++) {
        int rn = (tid >> 3) + i * 32;
        int ck = (tid & 7) * 8;
        bf16x8 v;
        #pragma unroll
        for (int j = 0; j < 8; j++) v[j] = (__bf16)tile[ck + j][rn];
        *(bf16x8*)(dst + (size_t)(n0 + rn) * DM + (k0 + ck)) = v;
    }
}

// ---------------- gather x rows into padded bf16 bins ----------------
__global__ void gather_kernel(const float* __restrict__ x,
                              const int* __restrict__ slot_token,
                              __bf16* __restrict__ xg)
{
    int slot = blockIdx.x;
    int tok = slot_token[slot];
    int c = threadIdx.x * 8;
    float f[8];
    if (tok >= 0) {
        const float4* px = (const float4*)(x + (size_t)tok * DM + c);
        float4 a = px[0], b = px[1];
        f[0] = a.x; f[1] = a.y; f[2] = a.z; f[3] = a.w;
        f[4] = b.x; f[5] = b.y; f[6] = b.z; f[7] = b.w;
    } else {
        #pragma unroll
        for (int i = 0; i < 8; i++) f[i] = 0.f;
    }
    bf16x8 v;
    #pragma unroll
    for (int i = 0; i < 8; i++) v[i] = (__bf16)f[i];
    *(bf16x8*)(xg + (size_t)slot * DM + c) = v;
}

// ---------------- grouped GEMM, 256-tile 4-phase counted-vmcnt schedule ----
// A: [MROWS][K] bf16 row-major. B1/B2: [E][N][K] bf16 (pre-transposed).
// FUSED: BN=128, C = silu(A@B1t) * (A@B2t); else BN=256, C = A@B1t.
// Grid: 1D, XCD-chunked bijective map; within a chunk, groups of
// (10 mt x 4 nt) with mt innermost so the B-slice stays L2-resident.
template<bool FUSED>
__global__ __launch_bounds__(512, 2)
void gemm8_kernel(const __bf16* __restrict__ A,
                  const __bf16* __restrict__ B1,
                  const __bf16* __restrict__ B2,
                  __bf16* __restrict__ C,
                  const int* __restrict__ counts)
{
    constexpr int K = 2048, N = 2048;
    constexpr int BM = 256;
    constexpr int BN = FUSED ? 128 : 256;
    constexpr int NTILES = N / BN;       // 16 or 8
    constexpr int NT = K / 64;           // 32 K-tiles
    constexpr int NJ = FUSED ? 2 : 4;    // N-fragments per wave (per B matrix)
    constexpr int ROWB = K * 2;          // 4096B global row stride

    extern __shared__ char smem[];       // 131072 bytes (2 x 64KB buffers)

    // ---- XCD-chunked, B-reuse-grouped mapping (bijective: nwg % 8 == 0) ----
    constexpr int PERE = BMTILES * NTILES;      // blocks per expert (160 / 80)
    constexpr int PERX = NEXP * PERE / 8;       // blocks per XCD chunk
    int w = (blockIdx.x % 8) * PERX + blockIdx.x / 8;
    int e = w / PERE;
    int r = w % PERE;
    int ntg = r / (BMTILES * 4);
    int rr  = r % (BMTILES * 4);
    int ntile = ntg * 4 + rr / BMTILES;
    int mtile = rr % BMTILES;

    int mloc = mtile * BM;
    int rows = counts[e]; if (rows > CAP) rows = CAP;
    if (mloc >= rows) return;            // expert bin empty in this tile

    int tid = threadIdx.x;
    int wid = tid >> 6, lane = tid & 63;
    int wm = wid & 1, wn = wid >> 1;     // 2 x 4 wave grid
    size_t rowBase = (size_t)e * CAP + mloc;

    // ---- staging source pointers (per-thread, swizzled chunk) ----
    int r0 = tid >> 3;                            // 0..63 rows per 8KB issue
    int sw = ((tid & 7) ^ (r0 & 7)) << 4;         // chunk swizzle
    const char* sA = (const char*)(A + (rowBase + r0) * (size_t)K) + sw;
    const char* sBu0; const char* sBu1;
    {
        size_t brow = (size_t)e * N + (size_t)ntile * BN + r0;
        sBu0 = (const char*)(B1 + brow * (size_t)K) + sw;
        if constexpr (FUSED) sBu1 = (const char*)(B2 + brow * (size_t)K) + sw;
        else                 sBu1 = sBu0 + 128 * ROWB;
    }
    char* lw = smem + wid * 1024;        // wave-uniform LDS base slice

    // one 16KB unit = 128 rows x 128B; 2 x global_load_lds(16B) per thread
    auto stage2 = [&](const char* s, int koff, int ldsOff) {
        load_lds16(s + koff, lw + ldsOff);
        load_lds16(s + koff + 64 * ROWB, lw + ldsOff + 8192);
    };

    // ---- fragment read offsets (swizzled) ----
    int xc0 = (((lane >> 4) + 0) ^ (lane & 7)) << 4;   // ks=0 16B chunk
    int xc1 = (((lane >> 4) + 4) ^ (lane & 7)) << 4;   // ks=1
    int aOff = (wm * 128 + (lane & 15)) * 128;
    int bOff1, bOff2 = 0;
    if constexpr (FUSED) {
        bOff1 = 32768 + (wn * 32 + (lane & 15)) * 128;
        bOff2 = bOff1 + 16384;
    } else {
        bOff1 = 32768 + (wn * 64 + (lane & 15)) * 128;
    }

    f32x4 acc1[8][NJ];
    f32x4 acc2[FUSED ? 8 : 1][NJ];
    #pragma unroll
    for (int i = 0; i < 8; i++)
        #pragma unroll
        for (int j = 0; j < NJ; j++) {
            acc1[i][j] = (f32x4){0.f, 0.f, 0.f, 0.f};
            if constexpr (FUSED) acc2[i][j] = (f32x4){0.f, 0.f, 0.f, 0.f};
        }

    // ---- prologue: tile0 fully + tile1 B-units; leave t1.B in flight ----
    stage2(sA,              0, 0);
    stage2(sA + 128 * ROWB, 0, 16384);
    stage2(sBu0,            0, 32768);
    stage2(sBu1,            0, 49152);
    stage2(sBu0,          128, 65536 + 32768);
    stage2(sBu1,          128, 65536 + 49152);
    asm volatile("s_waitcnt vmcnt(4)" ::: "memory");   // tile0 landed
    __builtin_amdgcn_sched_barrier(0);
    __builtin_amdgcn_s_barrier();

    bf16x8 b1f[NJ][2];
    bf16x8 b2f[FUSED ? NJ : 1][2];

    #pragma unroll 2
    for (int t = 0; t < NT; ++t) {
        int bufC = (t & 1) << 16;
        int bufO = bufC ^ 65536;
        #pragma unroll
        for (int p = 0; p < 4; ++p) {
            // --- ds_read register subtile ---
            bf16x8 a[2][2];
            #pragma unroll
            for (int i2 = 0; i2 < 2; ++i2) {
                const char* ap = smem + bufC + aOff + (2 * p + i2) * 2048;
                a[i2][0] = *(const bf16x8*)(ap + xc0);
                a[i2][1] = *(const bf16x8*)(ap + xc1);
            }
            if (p == 0) {   // all B fragments once per K-tile -> B region free after p0
                #pragma unroll
                for (int j = 0; j < NJ; ++j) {
                    const char* bp = smem + bufC + bOff1 + j * 2048;
                    b1f[j][0] = *(const bf16x8*)(bp + xc0);
                    b1f[j][1] = *(const bf16x8*)(bp + xc1);
                    if constexpr (FUSED) {
                        const char* bp2 = smem + bufC + bOff2 + j * 2048;
                        b2f[j][0] = *(const bf16x8*)(bp2 + xc0);
                        b2f[j][1] = *(const bf16x8*)(bp2 + xc1);
                    }
                }
            }
            // --- prefetch issue: A(t+1) at p0 (3-phase cover), B(t+2) at p1/p2 ---
            if (p == 0) {
                if (t + 1 < NT) {
                    stage2(sA,              (t + 1) * 128, bufO);
                    stage2(sA + 128 * ROWB, (t + 1) * 128, bufO + 16384);
                }
            } else if (p == 1) { if (t + 2 < NT) stage2(sBu0, (t + 2) * 128, bufC + 32768); }
            else if (p == 2)   { if (t + 2 < NT) stage2(sBu1, (t + 2) * 128, bufC + 49152); }

            __builtin_amdgcn_s_barrier();
            asm volatile("s_waitcnt lgkmcnt(0)" ::: "memory");
            __builtin_amdgcn_sched_barrier(0);
            __builtin_amdgcn_s_setprio(1);
            #pragma unroll
            for (int ks = 0; ks < 2; ++ks)
                #pragma unroll
                for (int i2 = 0; i2 < 2; ++i2)
                    #pragma unroll
                    for (int j = 0; j < NJ; ++j) {
                        acc1[2 * p + i2][j] = __builtin_amdgcn_mfma_f32_16x16x32_bf16(
                            a[i2][ks], b1f[j][ks], acc1[2 * p + i2][j], 0, 0, 0);
                        if constexpr (FUSED)
                            acc2[2 * p + i2][j] = __builtin_amdgcn_mfma_f32_16x16x32_bf16(
                                a[i2][ks], b2f[j][ks], acc2[2 * p + i2][j], 0, 0, 0);
                    }
            __builtin_amdgcn_s_setprio(0);
            __builtin_amdgcn_sched_barrier(0);
            if (p == 3) {   // tile boundary: keep only B(t+2)'s 4 loads in flight
                if (t + 2 < NT)      { asm volatile("s_waitcnt vmcnt(4)" ::: "memory"); }
                else if (t + 1 < NT) { asm volatile("s_waitcnt vmcnt(0)" ::: "memory"); }
                __builtin_amdgcn_sched_barrier(0);
            }
            __builtin_amdgcn_s_barrier();
        }
    }

    // ---- epilogue: C/D layout col = lane&15, row = (lane>>4)*4 + reg ----
    size_t crow0 = rowBase + wm * 128 + ((lane >> 4) << 2);
    int col0 = ntile * BN + wn * (FUSED ? 32 : 64) + (lane & 15);
    #pragma unroll
    for (int i = 0; i < 8; ++i)
        #pragma unroll
        for (int j = 0; j < NJ; ++j)
            #pragma unroll
            for (int r4 = 0; r4 < 4; ++r4) {
                float v = acc1[i][j][r4];
                if constexpr (FUSED) {
                    float z3 = acc2[i][j][r4];
                    v = (v / (1.f + __expf(-v))) * z3;   // silu(z1) * z3
                }
                C[(crow0 + i * 16 + r4) * (size_t)N + (col0 + j * 16)] = (__bf16)v;
            }
}

// ---------------- weighted combine back to tokens ----------------
__global__ void combine_kernel(const __bf16* __restrict__ y,
                               const int* __restrict__ assign_slot,
                               const float* __restrict__ ew,
                               float* __restrict__ out)
{
    int n = blockIdx.x;
    int s0 = assign_slot[2 * n], s1 = assign_slot[2 * n + 1];
    float w0 = ew[2 * n], w1 = ew[2 * n + 1];
    int c = threadIdx.x * 8;
    float acc[8];
    #pragma unroll
    for (int i = 0; i < 8; i++) acc[i] = 0.f;
    if (s0 >= 0) {
        bf16x8 v = *(const bf16x8*)(y + (size_t)s0 * DM + c);
        #pragma unroll
        for (int i = 0; i < 8; i++) acc[i] += w0 * (float)v[i];
    }
    if (s1 >= 0) {
        bf16x8 v = *(const bf16x8*)(y + (size_t)s1 * DM + c);
        #pragma unroll
        for (int i = 0; i < 8; i++) acc[i] += w1 * (float)v[i];
    }
    float4* po = (float4*)(out + (size_t)n * DM + c);
    po[0] = (float4){acc[0], acc[1], acc[2], acc[3]};
    po[1] = (float4){acc[4], acc[5], acc[6], acc[7]};
}

extern "C" void kernel_launch(void* const* d_in, const int* in_sizes, int n_in,
                              void* d_out, int out_size, void* d_ws, size_t ws_size,
                              hipStream_t stream)
{
    const float* x  = (const float*)d_in[0];
    const float* ew = (const float*)d_in[1];
    const int* eidx = (const int*)d_in[2];
    const float* w1 = (const float*)d_in[3];
    const float* w2 = (const float*)d_in[4];
    const float* w3 = (const float*)d_in[5];
    float* out = (float*)d_out;
    float* counts_out = out + (size_t)NTOK * DM;

    char* ws = (char*)d_ws;
    size_t off = 0;
    auto alloc = [&](size_t bytes) -> void* {
        off = (off + 255) & ~(size_t)255;
        void* p = ws + off;
        off += bytes;
        return p;
    };
    int* slot_token  = (int*)alloc((size_t)MROWS * 4);
    int* assign_slot = (int*)alloc((size_t)TASSIGN * 4);
    int* counts      = (int*)alloc(NEXP * 4);
    int* chunk_cnt   = (int*)alloc((size_t)RBLK * NEXP * 4);
    int* chunk_base  = (int*)alloc((size_t)RBLK * NEXP * 4);
    __bf16* xg  = (__bf16*)alloc((size_t)MROWS * DM * 2);
    __bf16* h   = (__bf16*)alloc((size_t)MROWS * DH * 2);
    __bf16* w1t = (__bf16*)alloc((size_t)NEXP * DM * DH * 2);
    __bf16* w3t = (__bf16*)alloc((size_t)NEXP * DM * DH * 2);
    __bf16* w2t = (__bf16*)alloc((size_t)NEXP * DM * DH * 2);
    __bf16* y = xg;  // xg dead after gemm1 -> reuse for y

    static int attr_done = 0;
    if (!attr_done) {
        hipFuncSetAttribute((const void*)gemm8_kernel<true>,
                            hipFuncAttributeMaxDynamicSharedMemorySize, 131072);
        hipFuncSetAttribute((const void*)gemm8_kernel<false>,
                            hipFuncAttributeMaxDynamicSharedMemorySize, 131072);
        attr_done = 1;
    }

    route_hist_kernel<<<RBLK, 256, 0, stream>>>(eidx, chunk_cnt, slot_token);
    route_scan_kernel<<<1, 64, 0, stream>>>(chunk_cnt, chunk_base, counts, counts_out);
    route_assign_kernel<<<RBLK, 256, 0, stream>>>(eidx, chunk_base, slot_token, assign_slot);
    transpose_kernel<<<dim3(32, 32, 24), 256, 0, stream>>>(w1, w3, w2, w1t, w3t, w2t);
    gather_kernel<<<MROWS, 256, 0, stream>>>(x, slot_token, xg);
    gemm8_kernel<true><<<NEXP * BMTILES * 16, 512, 131072, stream>>>(xg, w1t, w3t, h, counts);
    gemm8_kernel<false><<<NEXP * BMTILES * 8, 512, 131072, stream>>>(h, w2t, nullptr, y, counts);
    combine_kernel<<<NTOK, 256, 0, stream>>>(y, assign_slot, ew, out);
}

// Round 3
// 906.242 us; speedup vs baseline: 1.2988x; 1.0186x over previous
//
#include <hip/hip_runtime.h>
#include <hip/hip_bf16.h>
#include <stdint.h>

#define NTOK 8192
#define DM 2048
#define DH 2048
#define NEXP 8
#define TOPK 2
#define TASSIGN (NTOK * TOPK)   // 16384
#define CAP 2560                // int(1.25 * TOPK * NTOK / NEXP)
#define MROWS (NEXP * CAP)      // 20480
#define BMTILES 10              // CAP / 256
#define RBLK 64                 // routing chunks (256 assignments each)

using bf16x8 = __attribute__((ext_vector_type(8))) __bf16;
using f32x4  = __attribute__((ext_vector_type(4))) float;

__device__ __forceinline__ void load_lds16(const void* g, void* l) {
    __builtin_amdgcn_global_load_lds((const __attribute__((address_space(1))) void*)g,
                                     (__attribute__((address_space(3))) void*)l,
                                     16, 0, 0);
}

// ---------------- routing, split: hist -> scan -> assign ----------------
__global__ void route_hist_kernel(const int* __restrict__ eidx,
                                  int* __restrict__ chunk_cnt,
                                  int* __restrict__ slot_token)
{
    int b = blockIdx.x, tid = threadIdx.x, lane = tid & 63, wid = tid >> 6;
    __shared__ int wcnt[4][NEXP];
    for (int i = b * 320 + tid; i < (b + 1) * 320; i += 256) slot_token[i] = -1;
    int e = eidx[b * 256 + tid];
    #pragma unroll
    for (int ex = 0; ex < NEXP; ex++) {
        unsigned long long m = __ballot(e == ex);
        if (lane == 0) wcnt[wid][ex] = __popcll(m);
    }
    __syncthreads();
    if (tid < NEXP) {
        int s = 0;
        #pragma unroll
        for (int w = 0; w < 4; w++) s += wcnt[w][tid];
        chunk_cnt[b * NEXP + tid] = s;
    }
}

__global__ void route_scan_kernel(const int* __restrict__ chunk_cnt,
                                  int* __restrict__ chunk_base,
                                  int* __restrict__ counts,
                                  float* __restrict__ counts_out)
{
    int e = threadIdx.x;
    if (e < NEXP) {
        int run = 0;
        for (int b = 0; b < RBLK; b++) {
            chunk_base[b * NEXP + e] = run;
            run += chunk_cnt[b * NEXP + e];
        }
        counts[e] = run;
        counts_out[e] = (float)run;   // output 1 compared as float32
    }
}

__global__ void route_assign_kernel(const int* __restrict__ eidx,
                                    const int* __restrict__ chunk_base,
                                    int* __restrict__ slot_token,
                                    int* __restrict__ assign_slot)
{
    int b = blockIdx.x, tid = threadIdx.x, lane = tid & 63, wid = tid >> 6;
    __shared__ int wcnt[4][NEXP];
    int t = b * 256 + tid;
    int e = eidx[t];
    unsigned long long mymask = 0;
    #pragma unroll
    for (int ex = 0; ex < NEXP; ex++) {
        unsigned long long m = __ballot(e == ex);
        if (ex == e) mymask = m;
        if (lane == 0) wcnt[wid][ex] = __popcll(m);
    }
    int rankw = __popcll(mymask & ((1ull << lane) - 1ull));
    __syncthreads();
    int r = chunk_base[b * NEXP + e] + rankw;
    for (int w = 0; w < wid; w++) r += wcnt[w][e];
    int slot = (r < CAP) ? (e * CAP + r) : -1;
    assign_slot[t] = slot;
    if (slot >= 0) slot_token[slot] = t >> 1;  // token = assignment / TOPK
}

// ---------------- weight transpose + fp32->bf16 convert ----------------
__global__ void transpose_kernel(const float* __restrict__ wa,
                                 const float* __restrict__ wb,
                                 const float* __restrict__ wc,
                                 __bf16* __restrict__ wat,
                                 __bf16* __restrict__ wbt,
                                 __bf16* __restrict__ wct)
{
    __shared__ float tile[64][65];
    int z = blockIdx.z;
    int mat = z >> 3, e = z & 7;
    const float* src = (mat == 0 ? wa : mat == 1 ? wb : wc) + (size_t)e * DM * DH;
    __bf16* dst = (mat == 0 ? wat : mat == 1 ? wbt : wct) + (size_t)e * DM * DH;
    int k0 = blockIdx.x * 64, n0 = blockIdx.y * 64;
    int tid = threadIdx.x;
    #pragma unroll
    for (int i = 0; i < 16; i++) {
        int lin = tid + i * 256;
        int r = lin >> 6, c = lin & 63;
        tile[r][c] = src[(size_t)(k0 + r) * DH + (n0 + c)];
    }
    __syncthreads();
    #pragma unroll
    for (int i = 0; i < 2; i++) {
        int rn = (tid >> 3) + i * 32;
        int ck = (tid & 7) * 8;
        bf16x8 v;
        #pragma unroll
        for (int j = 0; j < 8; j++) v[j] = (__bf16)tile[ck + j][rn];
        *(bf16x8*)(dst + (size_t)(n0 + rn) * DM + (k0 + ck)) = v;
    }
}

// ---------------- gather x rows into padded bf16 bins ----------------
__global__ void gather_kernel(const float* __restrict__ x,
                              const int* __restrict__ slot_token,
                              __bf16* __restrict__ xg)
{
    int slot = blockIdx.x;
    int tok = slot_token[slot];
    int c = threadIdx.x * 8;
    float f[8];
    if (tok >= 0) {
        const float4* px = (const float4*)(x + (size_t)tok * DM + c);
        float4 a = px[0], b = px[1];
        f[0] = a.x; f[1] = a.y; f[2] = a.z; f[3] = a.w;
        f[4] = b.x; f[5] = b.y; f[6] = b.z; f[7] = b.w;
    } else {
        #pragma unroll
        for (int i = 0; i < 8; i++) f[i] = 0.f;
    }
    bf16x8 v;
    #pragma unroll
    for (int i = 0; i < 8; i++) v[i] = (__bf16)f[i];
    *(bf16x8*)(xg + (size_t)slot * DM + c) = v;
}

// ---------------- grouped GEMM: 256x128 tile, 1-barrier phases ----------
// A: [MROWS][K] bf16 row-major. B1/B2: [E][N][K] bf16 (pre-transposed).
// FUSED: C = silu(A@B1t) * (A@B2t), 4 phases/K-tile; else C = A@B1t,
// 2 phases/K-tile. One s_barrier per phase; counted vmcnt at tile end.
// LDS buffer (64KB stride): A [256][64] @0, B1 @32768, B2 @49152.
template<bool FUSED>
__global__ __launch_bounds__(512, 2)
void gemm8_kernel(const __bf16* __restrict__ A,
                  const __bf16* __restrict__ B1,
                  const __bf16* __restrict__ B2,
                  __bf16* __restrict__ C,
                  const int* __restrict__ counts)
{
    constexpr int K = 2048, N = 2048;
    constexpr int BM = 256, BN = 128;
    constexpr int NTILES = N / BN;       // 16
    constexpr int NT = K / 64;           // 32 K-tiles
    constexpr int ROWB = K * 2;          // 4096B global row stride

    extern __shared__ char smem[];       // 131072 bytes (2 x 64KB buffers)

    // ---- XCD-chunked, B-reuse-grouped bijective mapping ----
    constexpr int PERE = BMTILES * NTILES;      // 160 blocks per expert
    constexpr int PERX = NEXP * PERE / 8;       // 160 blocks per XCD chunk
    int w = (blockIdx.x % 8) * PERX + blockIdx.x / 8;
    int e = w / PERE;
    int r = w % PERE;
    int ntg = r / (BMTILES * 4);
    int rr  = r % (BMTILES * 4);
    int ntile = ntg * 4 + rr / BMTILES;
    int mtile = rr % BMTILES;

    int mloc = mtile * BM;
    int rows = counts[e]; if (rows > CAP) rows = CAP;
    if (mloc >= rows) return;

    int tid = threadIdx.x;
    int wid = tid >> 6, lane = tid & 63;
    int wm = wid & 1, wn = wid >> 1;     // 2 x 4 wave grid
    size_t rowBase = (size_t)e * CAP + mloc;

    // ---- staging source pointers (per-thread, swizzled chunk) ----
    int r0 = tid >> 3;
    int sw = ((tid & 7) ^ (r0 & 7)) << 4;
    const char* sA = (const char*)(A + (rowBase + r0) * (size_t)K) + sw;
    size_t brow = (size_t)e * N + (size_t)ntile * BN + r0;
    const char* sBu0 = (const char*)(B1 + brow * (size_t)K) + sw;
    const char* sBu1 = FUSED ? (const char*)(B2 + brow * (size_t)K) + sw : nullptr;
    char* lw = smem + wid * 1024;

    auto stage2 = [&](const char* s, int koff, int ldsOff) {
        load_lds16(s + koff, lw + ldsOff);
        load_lds16(s + koff + 64 * ROWB, lw + ldsOff + 8192);
    };

    // ---- fragment read offsets (swizzled) ----
    int xc0 = (((lane >> 4) + 0) ^ (lane & 7)) << 4;   // ks=0 16B chunk
    int xc1 = (((lane >> 4) + 4) ^ (lane & 7)) << 4;   // ks=1
    int aOff = (wm * 128 + (lane & 15)) * 128;
    int bOff1 = 32768 + (wn * 32 + (lane & 15)) * 128;
    int bOff2 = bOff1 + 16384;   // FUSED only

    f32x4 acc1[8][2];
    f32x4 acc2[FUSED ? 8 : 1][2];
    #pragma unroll
    for (int i = 0; i < 8; i++)
        #pragma unroll
        for (int j = 0; j < 2; j++) {
            acc1[i][j] = (f32x4){0.f, 0.f, 0.f, 0.f};
            if constexpr (FUSED) acc2[i][j] = (f32x4){0.f, 0.f, 0.f, 0.f};
        }

    // ---- prologue ----
    stage2(sA,              0, 0);
    stage2(sA + 128 * ROWB, 0, 16384);
    stage2(sBu0,            0, 32768);
    if constexpr (FUSED) {
        stage2(sBu1,   0, 49152);
        stage2(sBu0, 128, 65536 + 32768);
        stage2(sBu1, 128, 65536 + 49152);
        asm volatile("s_waitcnt vmcnt(4)" ::: "memory");
    } else {
        stage2(sBu0, 128, 65536 + 32768);
        asm volatile("s_waitcnt vmcnt(2)" ::: "memory");
    }
    __builtin_amdgcn_sched_barrier(0);
    __builtin_amdgcn_s_barrier();

    #pragma unroll 2
    for (int t = 0; t < NT; ++t) {
        int bufC = (t & 1) << 16;
        int bufO = bufC ^ 65536;
        const char* base = smem + bufC;

        if constexpr (FUSED) {
            bf16x8 a0[4], a1[4], bkA[4], bkB[4];
            // ---- p0: A i0-3 ks0 + B ks0; stage A(t+1) unit0 ----
            #pragma unroll
            for (int i = 0; i < 4; i++) a0[i] = *(const bf16x8*)(base + aOff + i * 2048 + xc0);
            bkA[0] = *(const bf16x8*)(base + bOff1 + 0    + xc0);
            bkA[1] = *(const bf16x8*)(base + bOff1 + 2048 + xc0);
            bkA[2] = *(const bf16x8*)(base + bOff2 + 0    + xc0);
            bkA[3] = *(const bf16x8*)(base + bOff2 + 2048 + xc0);
            if (t + 1 < NT) stage2(sA, (t + 1) * 128, bufO);
            asm volatile("s_waitcnt lgkmcnt(0)" ::: "memory");
            __builtin_amdgcn_sched_barrier(0);
            __builtin_amdgcn_s_setprio(1);
            #pragma unroll
            for (int i = 0; i < 4; i++) {
                acc1[i][0] = __builtin_amdgcn_mfma_f32_16x16x32_bf16(a0[i], bkA[0], acc1[i][0], 0, 0, 0);
                acc1[i][1] = __builtin_amdgcn_mfma_f32_16x16x32_bf16(a0[i], bkA[1], acc1[i][1], 0, 0, 0);
                acc2[i][0] = __builtin_amdgcn_mfma_f32_16x16x32_bf16(a0[i], bkA[2], acc2[i][0], 0, 0, 0);
                acc2[i][1] = __builtin_amdgcn_mfma_f32_16x16x32_bf16(a0[i], bkA[3], acc2[i][1], 0, 0, 0);
            }
            __builtin_amdgcn_s_setprio(0);
            __builtin_amdgcn_sched_barrier(0);
            __builtin_amdgcn_s_barrier();
            // ---- p1: A i4-7 ks0 + B ks1; stage A(t+1) unit1 ----
            #pragma unroll
            for (int i = 0; i < 4; i++) a1[i] = *(const bf16x8*)(base + aOff + (4 + i) * 2048 + xc0);
            bkB[0] = *(const bf16x8*)(base + bOff1 + 0    + xc1);
            bkB[1] = *(const bf16x8*)(base + bOff1 + 2048 + xc1);
            bkB[2] = *(const bf16x8*)(base + bOff2 + 0    + xc1);
            bkB[3] = *(const bf16x8*)(base + bOff2 + 2048 + xc1);
            if (t + 1 < NT) stage2(sA + 128 * ROWB, (t + 1) * 128, bufO + 16384);
            asm volatile("s_waitcnt lgkmcnt(0)" ::: "memory");
            __builtin_amdgcn_sched_barrier(0);
            __builtin_amdgcn_s_setprio(1);
            #pragma unroll
            for (int i = 0; i < 4; i++) {
                acc1[4 + i][0] = __builtin_amdgcn_mfma_f32_16x16x32_bf16(a1[i], bkA[0], acc1[4 + i][0], 0, 0, 0);
                acc1[4 + i][1] = __builtin_amdgcn_mfma_f32_16x16x32_bf16(a1[i], bkA[1], acc1[4 + i][1], 0, 0, 0);
                acc2[4 + i][0] = __builtin_amdgcn_mfma_f32_16x16x32_bf16(a1[i], bkA[2], acc2[4 + i][0], 0, 0, 0);
                acc2[4 + i][1] = __builtin_amdgcn_mfma_f32_16x16x32_bf16(a1[i], bkA[3], acc2[4 + i][1], 0, 0, 0);
            }
            __builtin_amdgcn_s_setprio(0);
            __builtin_amdgcn_sched_barrier(0);
            __builtin_amdgcn_s_barrier();
            // ---- p2: A i0-3 ks1 ----
            #pragma unroll
            for (int i = 0; i < 4; i++) a0[i] = *(const bf16x8*)(base + aOff + i * 2048 + xc1);
            asm volatile("s_waitcnt lgkmcnt(0)" ::: "memory");
            __builtin_amdgcn_sched_barrier(0);
            __builtin_amdgcn_s_setprio(1);
            #pragma unroll
            for (int i = 0; i < 4; i++) {
                acc1[i][0] = __builtin_amdgcn_mfma_f32_16x16x32_bf16(a0[i], bkB[0], acc1[i][0], 0, 0, 0);
                acc1[i][1] = __builtin_amdgcn_mfma_f32_16x16x32_bf16(a0[i], bkB[1], acc1[i][1], 0, 0, 0);
                acc2[i][0] = __builtin_amdgcn_mfma_f32_16x16x32_bf16(a0[i], bkB[2], acc2[i][0], 0, 0, 0);
                acc2[i][1] = __builtin_amdgcn_mfma_f32_16x16x32_bf16(a0[i], bkB[3], acc2[i][1], 0, 0, 0);
            }
            __builtin_amdgcn_s_setprio(0);
            __builtin_amdgcn_sched_barrier(0);
            __builtin_amdgcn_s_barrier();
            // ---- p3: A i4-7 ks1; stage B1/B2(t+2); vmcnt ----
            #pragma unroll
            for (int i = 0; i < 4; i++) a1[i] = *(const bf16x8*)(base + aOff + (4 + i) * 2048 + xc1);
            if (t + 2 < NT) {
                stage2(sBu0, (t + 2) * 128, bufC + 32768);
                stage2(sBu1, (t + 2) * 128, bufC + 49152);
            }
            asm volatile("s_waitcnt lgkmcnt(0)" ::: "memory");
            __builtin_amdgcn_sched_barrier(0);
            __builtin_amdgcn_s_setprio(1);
            #pragma unroll
            for (int i = 0; i < 4; i++) {
                acc1[4 + i][0] = __builtin_amdgcn_mfma_f32_16x16x32_bf16(a1[i], bkB[0], acc1[4 + i][0], 0, 0, 0);
                acc1[4 + i][1] = __builtin_amdgcn_mfma_f32_16x16x32_bf16(a1[i], bkB[1], acc1[4 + i][1], 0, 0, 0);
                acc2[4 + i][0] = __builtin_amdgcn_mfma_f32_16x16x32_bf16(a1[i], bkB[2], acc2[4 + i][0], 0, 0, 0);
                acc2[4 + i][1] = __builtin_amdgcn_mfma_f32_16x16x32_bf16(a1[i], bkB[3], acc2[4 + i][1], 0, 0, 0);
            }
            __builtin_amdgcn_s_setprio(0);
            __builtin_amdgcn_sched_barrier(0);
            if (t + 2 < NT)      { asm volatile("s_waitcnt vmcnt(4)" ::: "memory"); }
            else if (t + 1 < NT) { asm volatile("s_waitcnt vmcnt(0)" ::: "memory"); }
            __builtin_amdgcn_sched_barrier(0);
            __builtin_amdgcn_s_barrier();
        } else {
            bf16x8 a0[8], bk0[2], bk1[2];
            // ---- p0: A i0-7 ks0 + B ks0,ks1; stage A(t+1) both units ----
            #pragma unroll
            for (int i = 0; i < 8; i++) a0[i] = *(const bf16x8*)(base + aOff + i * 2048 + xc0);
            bk0[0] = *(const bf16x8*)(base + bOff1 + 0    + xc0);
            bk0[1] = *(const bf16x8*)(base + bOff1 + 2048 + xc0);
            bk1[0] = *(const bf16x8*)(base + bOff1 + 0    + xc1);
            bk1[1] = *(const bf16x8*)(base + bOff1 + 2048 + xc1);
            if (t + 1 < NT) {
                stage2(sA,              (t + 1) * 128, bufO);
                stage2(sA + 128 * ROWB, (t + 1) * 128, bufO + 16384);
            }
            asm volatile("s_waitcnt lgkmcnt(0)" ::: "memory");
            __builtin_amdgcn_sched_barrier(0);
            __builtin_amdgcn_s_setprio(1);
            #pragma unroll
            for (int i = 0; i < 8; i++) {
                acc1[i][0] = __builtin_amdgcn_mfma_f32_16x16x32_bf16(a0[i], bk0[0], acc1[i][0], 0, 0, 0);
                acc1[i][1] = __builtin_amdgcn_mfma_f32_16x16x32_bf16(a0[i], bk0[1], acc1[i][1], 0, 0, 0);
            }
            __builtin_amdgcn_s_setprio(0);
            __builtin_amdgcn_sched_barrier(0);
            __builtin_amdgcn_s_barrier();
            // ---- p1: A i0-7 ks1; stage B(t+2); vmcnt ----
            #pragma unroll
            for (int i = 0; i < 8; i++) a0[i] = *(const bf16x8*)(base + aOff + i * 2048 + xc1);
            if (t + 2 < NT) stage2(sBu0, (t + 2) * 128, bufC + 32768);
            asm volatile("s_waitcnt lgkmcnt(0)" ::: "memory");
            __builtin_amdgcn_sched_barrier(0);
            __builtin_amdgcn_s_setprio(1);
            #pragma unroll
            for (int i = 0; i < 8; i++) {
                acc1[i][0] = __builtin_amdgcn_mfma_f32_16x16x32_bf16(a0[i], bk1[0], acc1[i][0], 0, 0, 0);
                acc1[i][1] = __builtin_amdgcn_mfma_f32_16x16x32_bf16(a0[i], bk1[1], acc1[i][1], 0, 0, 0);
            }
            __builtin_amdgcn_s_setprio(0);
            __builtin_amdgcn_sched_barrier(0);
            if (t + 2 < NT)      { asm volatile("s_waitcnt vmcnt(2)" ::: "memory"); }
            else if (t + 1 < NT) { asm volatile("s_waitcnt vmcnt(0)" ::: "memory"); }
            __builtin_amdgcn_sched_barrier(0);
            __builtin_amdgcn_s_barrier();
        }
    }

    // ---- epilogue: C/D layout col = lane&15, row = (lane>>4)*4 + reg ----
    size_t crow0 = rowBase + wm * 128 + ((lane >> 4) << 2);
    int col0 = ntile * BN + wn * 32 + (lane & 15);
    #pragma unroll
    for (int i = 0; i < 8; ++i)
        #pragma unroll
        for (int j = 0; j < 2; ++j)
            #pragma unroll
            for (int r4 = 0; r4 < 4; ++r4) {
                float v = acc1[i][j][r4];
                if constexpr (FUSED) {
                    float z3 = acc2[i][j][r4];
                    v = (v / (1.f + __expf(-v))) * z3;   // silu(z1) * z3
                }
                C[(crow0 + i * 16 + r4) * (size_t)N + (col0 + j * 16)] = (__bf16)v;
            }
}

// ---------------- weighted combine back to tokens ----------------
__global__ void combine_kernel(const __bf16* __restrict__ y,
                               const int* __restrict__ assign_slot,
                               const float* __restrict__ ew,
                               float* __restrict__ out)
{
    int n = blockIdx.x;
    int s0 = assign_slot[2 * n], s1 = assign_slot[2 * n + 1];
    float w0 = ew[2 * n], w1 = ew[2 * n + 1];
    int c = threadIdx.x * 8;
    float acc[8];
    #pragma unroll
    for (int i = 0; i < 8; i++) acc[i] = 0.f;
    if (s0 >= 0) {
        bf16x8 v = *(const bf16x8*)(y + (size_t)s0 * DM + c);
        #pragma unroll
        for (int i = 0; i < 8; i++) acc[i] += w0 * (float)v[i];
    }
    if (s1 >= 0) {
        bf16x8 v = *(const bf16x8*)(y + (size_t)s1 * DM + c);
        #pragma unroll
        for (int i = 0; i < 8; i++) acc[i] += w1 * (float)v[i];
    }
    float4* po = (float4*)(out + (size_t)n * DM + c);
    po[0] = (float4){acc[0], acc[1], acc[2], acc[3]};
    po[1] = (float4){acc[4], acc[5], acc[6], acc[7]};
}

extern "C" void kernel_launch(void* const* d_in, const int* in_sizes, int n_in,
                              void* d_out, int out_size, void* d_ws, size_t ws_size,
                              hipStream_t stream)
{
    const float* x  = (const float*)d_in[0];
    const float* ew = (const float*)d_in[1];
    const int* eidx = (const int*)d_in[2];
    const float* w1 = (const float*)d_in[3];
    const float* w2 = (const float*)d_in[4];
    const float* w3 = (const float*)d_in[5];
    float* out = (float*)d_out;
    float* counts_out = out + (size_t)NTOK * DM;

    char* ws = (char*)d_ws;
    size_t off = 0;
    auto alloc = [&](size_t bytes) -> void* {
        off = (off + 255) & ~(size_t)255;
        void* p = ws + off;
        off += bytes;
        return p;
    };
    int* slot_token  = (int*)alloc((size_t)MROWS * 4);
    int* assign_slot = (int*)alloc((size_t)TASSIGN * 4);
    int* counts      = (int*)alloc(NEXP * 4);
    int* chunk_cnt   = (int*)alloc((size_t)RBLK * NEXP * 4);
    int* chunk_base  = (int*)alloc((size_t)RBLK * NEXP * 4);
    __bf16* xg  = (__bf16*)alloc((size_t)MROWS * DM * 2);
    __bf16* h   = (__bf16*)alloc((size_t)MROWS * DH * 2);
    __bf16* w1t = (__bf16*)alloc((size_t)NEXP * DM * DH * 2);
    __bf16* w3t = (__bf16*)alloc((size_t)NEXP * DM * DH * 2);
    __bf16* w2t = (__bf16*)alloc((size_t)NEXP * DM * DH * 2);
    __bf16* y = xg;  // xg dead after gemm1 -> reuse for y

    static int attr_done = 0;
    if (!attr_done) {
        hipFuncSetAttribute((const void*)gemm8_kernel<true>,
                            hipFuncAttributeMaxDynamicSharedMemorySize, 131072);
        hipFuncSetAttribute((const void*)gemm8_kernel<false>,
                            hipFuncAttributeMaxDynamicSharedMemorySize, 131072);
        attr_done = 1;
    }

    route_hist_kernel<<<RBLK, 256, 0, stream>>>(eidx, chunk_cnt, slot_token);
    route_scan_kernel<<<1, 64, 0, stream>>>(chunk_cnt, chunk_base, counts, counts_out);
    route_assign_kernel<<<RBLK, 256, 0, stream>>>(eidx, chunk_base, slot_token, assign_slot);
    transpose_kernel<<<dim3(32, 32, 24), 256, 0, stream>>>(w1, w3, w2, w1t, w3t, w2t);
    gather_kernel<<<MROWS, 256, 0, stream>>>(x, slot_token, xg);
    gemm8_kernel<true><<<NEXP * BMTILES * 16, 512, 131072, stream>>>(xg, w1t, w3t, h, counts);
    gemm8_kernel<false><<<NEXP * BMTILES * 16, 512, 131072, stream>>>(h, w2t, nullptr, y, counts);
    combine_kernel<<<NTOK, 256, 0, stream>>>(y, assign_slot, ew, out);
}